// Round 1
// baseline (1392.337 us; speedup 1.0000x reference)
//
#include <hip/hip_runtime.h>
#include <math.h>

#define NN 50000
#define NE 800000

// ---------------- zero fill ----------------
__global__ __launch_bounds__(256) void zero_f32(float* __restrict__ p, long n) {
    long i = (long)blockIdx.x * blockDim.x + threadIdx.x;
    long stride = (long)gridDim.x * blockDim.x;
    float4 z = make_float4(0.f, 0.f, 0.f, 0.f);
    for (long j = i * 4; j < n; j += stride * 4) {
        *(float4*)&p[j] = z;   // n is a multiple of 4 here
    }
}

// ---------------- C[M,64] = A[M,K] @ B[K,64], f32 ----------------
// block 256 threads; block tile 64 rows x 64 cols; K-tile 64.
__global__ __launch_bounds__(256) void gemm_n64(
    const float* __restrict__ A, const float* __restrict__ B,
    float* __restrict__ C, int M, int K)
{
    __shared__ float At[64][68];   // [k][r], padded to 68 (16B-aligned rows, conflict-light)
    __shared__ float Bs[64][64];   // [k][c]
    const int tid = threadIdx.x;
    const int row0 = blockIdx.x * 64;
    const int tc = tid & 15;        // 16 thread-cols x 4 = 64 cols
    const int tr = tid >> 4;        // 16 thread-rows x 4 = 64 rows
    float acc[4][4] = {};

    for (int k0 = 0; k0 < K; k0 += 64) {
        // ---- stage A: 64 rows x 64 k, transposed into At[k][r] ----
        {
            const int r  = tid >> 2;            // 0..63
            const int kq = (tid & 3) * 4;       // 0,4,8,12
            int row = row0 + r; if (row >= M) row = M - 1;   // clamp; garbage rows never written
            #pragma unroll
            for (int p = 0; p < 4; ++p) {
                int kk = kq + 16 * p;
                int kg = k0 + kk;
                float4 v;
                if (kg + 3 < K) {
                    v = *(const float4*)&A[(size_t)row * K + kg];
                } else {
                    v.x = (kg + 0 < K) ? A[(size_t)row * K + kg + 0] : 0.f;
                    v.y = (kg + 1 < K) ? A[(size_t)row * K + kg + 1] : 0.f;
                    v.z = (kg + 2 < K) ? A[(size_t)row * K + kg + 2] : 0.f;
                    v.w = (kg + 3 < K) ? A[(size_t)row * K + kg + 3] : 0.f;
                }
                At[kk + 0][r] = v.x; At[kk + 1][r] = v.y;
                At[kk + 2][r] = v.z; At[kk + 3][r] = v.w;
            }
        }
        // ---- stage B: 64 k x 64 c ----
        {
            const int kk = tid >> 2;            // 0..63
            const int cq = (tid & 3) * 4;
            int kg = k0 + kk;
            #pragma unroll
            for (int p = 0; p < 4; ++p) {
                int c = cq + 16 * p;
                float4 v = make_float4(0.f, 0.f, 0.f, 0.f);
                if (kg < K) v = *(const float4*)&B[(size_t)kg * 64 + c];
                *(float4*)&Bs[kk][c] = v;
            }
        }
        __syncthreads();
        #pragma unroll 8
        for (int k = 0; k < 64; ++k) {
            float4 a = *(const float4*)&At[k][tr * 4];
            float4 b = *(const float4*)&Bs[k][tc * 4];
            float av[4] = {a.x, a.y, a.z, a.w};
            float bv[4] = {b.x, b.y, b.z, b.w};
            #pragma unroll
            for (int i = 0; i < 4; ++i)
                #pragma unroll
                for (int j = 0; j < 4; ++j)
                    acc[i][j] += av[i] * bv[j];
        }
        __syncthreads();
    }
    #pragma unroll
    for (int i = 0; i < 4; ++i) {
        int row = row0 + tr * 4 + i;
        if (row < M) {
            float4 v = make_float4(acc[i][0], acc[i][1], acc[i][2], acc[i][3]);
            *(float4*)&C[(size_t)row * 64 + tc * 4] = v;
        }
    }
}

// ---------------- C[M,Nc] = S[M,64] @ W[64,Nc], f32 ----------------
// block 256; tile 32 rows x 128 cols; K=64 staged fully.
__global__ __launch_bounds__(256) void gemm_dec(
    const float* __restrict__ S, const float* __restrict__ W,
    float* __restrict__ C, int M, int Nc)
{
    __shared__ float St[64][36];     // [k][r], padded
    __shared__ float Ws[64][128];    // [k][c]
    const int tid = threadIdx.x;
    const int row0 = blockIdx.x * 32;
    const int c0 = blockIdx.y * 128;

    // stage S (32 rows x 64 k, transposed)
    {
        const int r  = tid >> 3;            // 0..31
        const int kq = (tid & 7) * 4;       // 0..28
        int row = row0 + r; if (row >= M) row = M - 1;
        #pragma unroll
        for (int p = 0; p < 2; ++p) {
            int kk = kq + 32 * p;
            float4 v = *(const float4*)&S[(size_t)row * 64 + kk];
            St[kk + 0][r] = v.x; St[kk + 1][r] = v.y;
            St[kk + 2][r] = v.z; St[kk + 3][r] = v.w;
        }
    }
    // stage W (64 k x 128 c)
    {
        const int kr = tid >> 5;            // 0..7
        const int cq = (tid & 31) * 4;      // 0..124
        #pragma unroll
        for (int p = 0; p < 8; ++p) {
            int k = kr + 8 * p;
            int c = c0 + cq;
            float4 v = make_float4(0.f, 0.f, 0.f, 0.f);
            if (c < Nc) v = *(const float4*)&W[(size_t)k * Nc + c];  // Nc%4==0, c%4==0 -> safe
            *(float4*)&Ws[k][cq] = v;
        }
    }
    __syncthreads();

    const int tc = tid & 31;    // 32 x 4 = 128 cols
    const int tr = tid >> 5;    // 8 x 4 = 32 rows
    float acc[4][4] = {};
    #pragma unroll 16
    for (int k = 0; k < 64; ++k) {
        float4 a = *(const float4*)&St[k][tr * 4];
        float4 b = *(const float4*)&Ws[k][tc * 4];
        float av[4] = {a.x, a.y, a.z, a.w};
        float bv[4] = {b.x, b.y, b.z, b.w};
        #pragma unroll
        for (int i = 0; i < 4; ++i)
            #pragma unroll
            for (int j = 0; j < 4; ++j)
                acc[i][j] += av[i] * bv[j];
    }
    #pragma unroll
    for (int i = 0; i < 4; ++i) {
        int row = row0 + tr * 4 + i;
        int c = c0 + tc * 4;
        if (row < M && c < Nc) {
            float4 v = make_float4(acc[i][0], acc[i][1], acc[i][2], acc[i][3]);
            *(float4*)&C[(size_t)row * Nc + c] = v;
        }
    }
}

// ---------------- out[N,64] += scatter(w * x[cols]) ----------------
// wave per edge (grid-stride), lane per column, atomic scatter.
__global__ __launch_bounds__(256) void spmm64(
    const int* __restrict__ rows, const int* __restrict__ cols,
    const float* __restrict__ w, const float* __restrict__ x,
    float* __restrict__ out, int nE)
{
    const int lane = threadIdx.x & 63;
    int wid = (blockIdx.x * 256 + threadIdx.x) >> 6;
    const int nw = (gridDim.x * 256) >> 6;
    for (int e = wid; e < nE; e += nw) {
        int r = rows[e];           // wave-uniform
        int c = cols[e];
        float wt = w[e];
        float v = wt * x[(size_t)c * 64 + lane];
        atomicAdd(&out[(size_t)r * 64 + lane], v);
    }
}

// ---------------- attention fusion ----------------
// wave per node; lane j owns column j.
__global__ __launch_bounds__(256) void attn_fuse(
    const float* __restrict__ e1, const float* __restrict__ e2,
    const float* __restrict__ Wo, const float* __restrict__ uo,
    float* __restrict__ emb, float* __restrict__ alpha, int n)
{
    const int lane = threadIdx.x & 63;
    const int node = (blockIdx.x * 256 + threadIdx.x) >> 6;
    if (node >= n) return;

    const size_t base = (size_t)node * 64;
    float e1v = e1[base + lane];
    float e2v = e2[base + lane];

    float acc1 = 0.f, acc2 = 0.f;
    for (int k = 0; k < 64; ++k) {
        float wv = Wo[k * 64 + lane];           // coalesced, L1-hot (16KB)
        acc1 += e1[base + k] * wv;              // wave-uniform load
        acc2 += e2[base + k] * wv;
    }
    float u = uo[lane];
    float t1 = tanhf(acc1) * u;
    float t2 = tanhf(acc2) * u;
    #pragma unroll
    for (int off = 32; off; off >>= 1) {
        t1 += __shfl_xor(t1, off);
        t2 += __shfl_xor(t2, off);
    }
    float m = fmaxf(t1, t2);
    float a1 = expf(t1 - m), a2 = expf(t2 - m);
    float s = a1 + a2;
    a1 /= s; a2 /= s;

    emb[base + lane] = a1 * e1v + a2 * e2v;
    if (lane == 0) {
        alpha[(size_t)node * 2 + 0] = a1;
        alpha[(size_t)node * 2 + 1] = a2;
    }
}

extern "C" void kernel_launch(void* const* d_in, const int* in_sizes, int n_in,
                              void* d_out, int out_size, void* d_ws, size_t ws_size,
                              hipStream_t stream)
{
    const float* omics1 = (const float*)d_in[0];
    const float* omics2 = (const float*)d_in[1];
    const int*   ei1    = (const int*)d_in[2];    // rows at [0,E), cols at [E,2E)
    const float* ew1    = (const float*)d_in[3];
    const int*   ei2    = (const int*)d_in[4];
    const float* ew2    = (const float*)d_in[5];
    const float* Wenc1  = (const float*)d_in[6];  // (2000,64)
    const float* Wenc2  = (const float*)d_in[7];  // (500,64)
    const float* womega = (const float*)d_in[8];  // (64,64)
    const float* uomega = (const float*)d_in[9];  // (64,1)
    const float* Wdec1  = (const float*)d_in[10]; // (64,2000)
    const float* Wdec2  = (const float*)d_in[11]; // (64,500)

    float* out  = (float*)d_out;
    float* e1   = out;
    float* e2   = e1 + (size_t)NN * 64;
    float* emb  = e2 + (size_t)NN * 64;
    float* alph = emb + (size_t)NN * 64;
    float* d1   = alph + (size_t)NN * 2;
    float* d2   = d1 + (size_t)NN * 2000;

    float* h1 = (float*)d_ws;             // (N,64) — reused as s1
    float* h2 = h1 + (size_t)NN * 64;     // (N,64) — reused as s2

    dim3 b256(256);

    // encoders: h = omics @ W_enc
    gemm_n64<<<dim3((NN + 63) / 64), b256, 0, stream>>>(omics1, Wenc1, h1, NN, 2000);
    gemm_n64<<<dim3((NN + 63) / 64), b256, 0, stream>>>(omics2, Wenc2, h2, NN, 500);

    // e1/e2 = spmm (zero first: atomics accumulate)
    zero_f32<<<2048, b256, 0, stream>>>(e1, (long)2 * NN * 64);
    spmm64<<<4096, b256, 0, stream>>>(ei1, ei1 + NE, ew1, h1, e1, NE);
    spmm64<<<4096, b256, 0, stream>>>(ei2, ei2 + NE, ew2, h2, e2, NE);

    // attention fusion -> emb, alpha
    attn_fuse<<<dim3((NN + 3) / 4), b256, 0, stream>>>(e1, e2, womega, uomega, emb, alph, NN);

    // s1/s2 = spmm(edge, emb)  [decoder spmm hoisted before the dense GEMM]
    zero_f32<<<2048, b256, 0, stream>>>(h1, (long)2 * NN * 64);
    spmm64<<<4096, b256, 0, stream>>>(ei1, ei1 + NE, ew1, emb, h1, NE);
    spmm64<<<4096, b256, 0, stream>>>(ei2, ei2 + NE, ew2, emb, h2, NE);

    // decoders: d = s @ W_dec
    gemm_dec<<<dim3((NN + 31) / 32, (2000 + 127) / 128), b256, 0, stream>>>(h1, Wdec1, d1, NN, 2000);
    gemm_dec<<<dim3((NN + 31) / 32, (500 + 127) / 128), b256, 0, stream>>>(h2, Wdec2, d2, NN, 500);
}

// Round 2
// 946.246 us; speedup vs baseline: 1.4714x; 1.4714x over previous
//
#include <hip/hip_runtime.h>
#include <math.h>

#define NN 50000
#define NE 800000

typedef __attribute__((ext_vector_type(8))) short bf16x8;
typedef __attribute__((ext_vector_type(4))) float f32x4;

__device__ __forceinline__ ushort f2bf(float f) {
    union { float f; unsigned u; } v; v.f = f;
    unsigned r = v.u + 0x7FFFu + ((v.u >> 16) & 1u);   // RNE
    return (ushort)(r >> 16);
}

// ---------------- zero int buffer ----------------
__global__ __launch_bounds__(256) void zero_i32(int* __restrict__ p, int n) {
    int i = blockIdx.x * 256 + threadIdx.x;
    if (i < n) p[i] = 0;
}

// ---------------- histogram of rows, both edge sets ----------------
__global__ __launch_bounds__(256) void hist2(const int* __restrict__ r1, const int* __restrict__ r2,
                                             int* __restrict__ c1, int* __restrict__ c2) {
    int i = blockIdx.x * 256 + threadIdx.x;
    if (i < NE) atomicAdd(&c1[r1[i]], 1);
    else { i -= NE; if (i < NE) atomicAdd(&c2[r2[i]], 1); }
}

// ---------------- exclusive scan (one block per edge set) ----------------
__global__ __launch_bounds__(1024) void scan2(const int* __restrict__ c1, const int* __restrict__ c2,
                                              int* __restrict__ rp1, int* __restrict__ rp2,
                                              int* __restrict__ cur1, int* __restrict__ cur2, int n) {
    const int* counts = blockIdx.x == 0 ? c1 : c2;
    int* rowptr = blockIdx.x == 0 ? rp1 : rp2;
    int* cursor = blockIdx.x == 0 ? cur1 : cur2;

    __shared__ int wsum[16];
    int t = threadIdx.x;
    const int chunk = (n + 1023) / 1024;
    int lo = t * chunk; int hi = lo + chunk; if (hi > n) hi = n; if (lo > n) lo = n;
    int s = 0;
    for (int i = lo; i < hi; ++i) s += counts[i];

    int lane = t & 63, w = t >> 6;
    int incl = s;
    #pragma unroll
    for (int off = 1; off < 64; off <<= 1) {
        int v = __shfl_up(incl, off);
        if (lane >= off) incl += v;
    }
    if (lane == 63) wsum[w] = incl;
    __syncthreads();
    if (w == 0 && lane < 16) {
        int v = wsum[lane];
        int iv = v;
        #pragma unroll
        for (int off = 1; off < 16; off <<= 1) {
            int u = __shfl_up(iv, off);
            if (lane >= off) iv += u;
        }
        wsum[lane] = iv - v;   // exclusive
    }
    __syncthreads();
    int off = wsum[w] + incl - s;
    for (int i = lo; i < hi; ++i) { rowptr[i] = off; cursor[i] = off; off += counts[i]; }
    if (t == 1023) rowptr[n] = off;
}

// ---------------- scatter into CSR order, both sets ----------------
__global__ __launch_bounds__(256) void scatter2(
    const int* __restrict__ r1, const int* __restrict__ ce1, const float* __restrict__ w1,
    int* __restrict__ cur1, int* __restrict__ sc1, float* __restrict__ sw1,
    const int* __restrict__ r2, const int* __restrict__ ce2, const float* __restrict__ w2,
    int* __restrict__ cur2, int* __restrict__ sc2, float* __restrict__ sw2) {
    int i = blockIdx.x * 256 + threadIdx.x;
    if (i < NE) {
        int p = atomicAdd(&cur1[r1[i]], 1);
        sc1[p] = ce1[i]; sw1[p] = w1[i];
    } else {
        i -= NE;
        if (i < NE) {
            int p = atomicAdd(&cur2[r2[i]], 1);
            sc2[p] = ce2[i]; sw2[p] = w2[i];
        }
    }
}

// ---------------- CSR spmm: out[row][0..63] = sum w * x[col][0..63] ----------------
__global__ __launch_bounds__(256) void spmm_csr(
    const int* __restrict__ rowptr, const int* __restrict__ sc, const float* __restrict__ sw,
    const float* __restrict__ x, float* __restrict__ out, int n) {
    const int lane = threadIdx.x & 63;
    const int row = (blockIdx.x * 256 + threadIdx.x) >> 6;
    if (row >= n) return;
    int beg = rowptr[row], end = rowptr[row + 1];
    float acc = 0.f;
    int i = beg;
    for (; i + 1 < end; i += 2) {
        int ca = sc[i], cb = sc[i + 1];
        float wa = sw[i], wb = sw[i + 1];
        float xa = x[(size_t)ca * 64 + lane];
        float xb = x[(size_t)cb * 64 + lane];
        acc += wa * xa;
        acc += wb * xb;
    }
    if (i < end) acc += sw[i] * x[(size_t)sc[i] * 64 + lane];
    out[(size_t)row * 64 + lane] = acc;
}

// ---------------- C[M,64] = A[M,K] @ B[K,64], bf16 MFMA, f32 acc ----------------
// block 256 (4 waves); tile 64 rows x 64 cols; K-tile 64.
__global__ __launch_bounds__(256) void gemm_enc(
    const float* __restrict__ A, const float* __restrict__ B,
    float* __restrict__ C, int M, int K) {
    __shared__ ushort Abf[64][72];   // [row][k], +8 pad (2-way LDS aliasing max)
    __shared__ ushort Bt[64][72];    // [col][k]
    const int tid = threadIdx.x;
    const int wid = tid >> 6, lane = tid & 63;
    const int row0 = blockIdx.x * 64;
    f32x4 acc[4] = {};

    for (int k0 = 0; k0 < K; k0 += 64) {
        // stage A: 64 rows x 64 k -> bf16
        {
            int r = tid >> 2;
            int row = row0 + r; if (row >= M) row = M - 1;
            int kq = (tid & 3) * 16;
            const float* src = A + (size_t)row * K;
            #pragma unroll
            for (int p = 0; p < 2; ++p) {
                int kk = kq + p * 8;
                int kg = k0 + kk;
                float v[8];
                if (kg + 7 < K) {
                    f32x4 a = *(const f32x4*)(src + kg);
                    f32x4 b = *(const f32x4*)(src + kg + 4);
                    v[0] = a.x; v[1] = a.y; v[2] = a.z; v[3] = a.w;
                    v[4] = b.x; v[5] = b.y; v[6] = b.z; v[7] = b.w;
                } else {
                    #pragma unroll
                    for (int j = 0; j < 8; ++j) v[j] = (kg + j < K) ? src[kg + j] : 0.f;
                }
                ushort u[8];
                #pragma unroll
                for (int j = 0; j < 8; ++j) u[j] = f2bf(v[j]);
                *(bf16x8*)&Abf[r][kk] = *(bf16x8*)u;
            }
        }
        // stage B transposed: Bt[col][k]
        {
            int kk = tid >> 2;
            int kg = k0 + kk;
            int cq = (tid & 3) * 16;
            #pragma unroll
            for (int p = 0; p < 4; ++p) {
                int c = cq + p * 4;
                float4 v = make_float4(0.f, 0.f, 0.f, 0.f);
                if (kg < K) v = *(const float4*)&B[(size_t)kg * 64 + c];
                Bt[c + 0][kk] = f2bf(v.x);
                Bt[c + 1][kk] = f2bf(v.y);
                Bt[c + 2][kk] = f2bf(v.z);
                Bt[c + 3][kk] = f2bf(v.w);
            }
        }
        __syncthreads();
        {
            int arow = wid * 16 + (lane & 15);
            int kg8 = (lane >> 4) * 8;
            #pragma unroll
            for (int kk = 0; kk < 64; kk += 32) {
                bf16x8 af = *(const bf16x8*)&Abf[arow][kk + kg8];
                #pragma unroll
                for (int ct = 0; ct < 4; ++ct) {
                    bf16x8 bfr = *(const bf16x8*)&Bt[ct * 16 + (lane & 15)][kk + kg8];
                    acc[ct] = __builtin_amdgcn_mfma_f32_16x16x32_bf16(af, bfr, acc[ct], 0, 0, 0);
                }
            }
        }
        __syncthreads();
    }
    // write: row = row0 + wid*16 + (lane>>4)*4 + r ; col = ct*16 + (lane&15)
    int rbase = row0 + wid * 16 + (lane >> 4) * 4;
    int cb = lane & 15;
    #pragma unroll
    for (int ct = 0; ct < 4; ++ct) {
        #pragma unroll
        for (int r = 0; r < 4; ++r) {
            int row = rbase + r;
            if (row < M) C[(size_t)row * 64 + ct * 16 + cb] = acc[ct][r];
        }
    }
}

// ---------------- C[M,Nc] = S[M,64] @ W[64,Nc], bf16 MFMA ----------------
// block 256 (4 waves); tile 64 rows x 128 cols; K = 64 (single shot).
__global__ __launch_bounds__(256) void gemm_dec(
    const float* __restrict__ S, const float* __restrict__ W,
    float* __restrict__ C, int M, int Nc) {
    __shared__ ushort Sbf[64][72];   // [row][k]
    __shared__ ushort Wt[128][72];   // [col][k]
    const int tid = threadIdx.x;
    const int wid = tid >> 6, lane = tid & 63;
    const int row0 = blockIdx.x * 64;
    const int c0 = blockIdx.y * 128;

    // stage S
    {
        int r = tid >> 2;
        int row = row0 + r; if (row >= M) row = M - 1;
        int kq = (tid & 3) * 16;
        const float* src = S + (size_t)row * 64;
        #pragma unroll
        for (int p = 0; p < 2; ++p) {
            int kk = kq + p * 8;
            f32x4 a = *(const f32x4*)(src + kk);
            f32x4 b = *(const f32x4*)(src + kk + 4);
            ushort u[8];
            u[0] = f2bf(a.x); u[1] = f2bf(a.y); u[2] = f2bf(a.z); u[3] = f2bf(a.w);
            u[4] = f2bf(b.x); u[5] = f2bf(b.y); u[6] = f2bf(b.z); u[7] = f2bf(b.w);
            *(bf16x8*)&Sbf[r][kk] = *(bf16x8*)u;
        }
    }
    // stage W transposed: Wt[c][k], c local 0..127
    {
        int k = tid >> 2;
        int cq = (tid & 3) * 32;
        const float* src = W + (size_t)k * Nc;
        #pragma unroll
        for (int p = 0; p < 8; ++p) {
            int c = cq + p * 4;
            int cg = c0 + c;
            float4 v = make_float4(0.f, 0.f, 0.f, 0.f);
            if (cg + 3 < Nc) v = *(const float4*)&src[cg];
            else {
                if (cg + 0 < Nc) v.x = src[cg + 0];
                if (cg + 1 < Nc) v.y = src[cg + 1];
                if (cg + 2 < Nc) v.z = src[cg + 2];
                if (cg + 3 < Nc) v.w = src[cg + 3];
            }
            Wt[c + 0][k] = f2bf(v.x);
            Wt[c + 1][k] = f2bf(v.y);
            Wt[c + 2][k] = f2bf(v.z);
            Wt[c + 3][k] = f2bf(v.w);
        }
    }
    __syncthreads();

    f32x4 acc[8] = {};
    {
        int arow = wid * 16 + (lane & 15);
        int kg8 = (lane >> 4) * 8;
        #pragma unroll
        for (int kk = 0; kk < 64; kk += 32) {
            bf16x8 af = *(const bf16x8*)&Sbf[arow][kk + kg8];
            #pragma unroll
            for (int ct = 0; ct < 8; ++ct) {
                bf16x8 bfr = *(const bf16x8*)&Wt[ct * 16 + (lane & 15)][kk + kg8];
                acc[ct] = __builtin_amdgcn_mfma_f32_16x16x32_bf16(af, bfr, acc[ct], 0, 0, 0);
            }
        }
    }
    int rbase = row0 + wid * 16 + (lane >> 4) * 4;
    int cb = lane & 15;
    #pragma unroll
    for (int ct = 0; ct < 8; ++ct) {
        #pragma unroll
        for (int r = 0; r < 4; ++r) {
            int row = rbase + r;
            int col = c0 + ct * 16 + cb;
            if (row < M && col < Nc) C[(size_t)row * Nc + col] = acc[ct][r];
        }
    }
}

// ---------------- attention fusion ----------------
__global__ __launch_bounds__(256) void attn_fuse(
    const float* __restrict__ e1, const float* __restrict__ e2,
    const float* __restrict__ Wo, const float* __restrict__ uo,
    float* __restrict__ emb, float* __restrict__ alpha, int n) {
    const int lane = threadIdx.x & 63;
    const int node = (blockIdx.x * 256 + threadIdx.x) >> 6;
    if (node >= n) return;

    const size_t base = (size_t)node * 64;
    float e1v = e1[base + lane];
    float e2v = e2[base + lane];

    float acc1 = 0.f, acc2 = 0.f;
    for (int k = 0; k < 64; ++k) {
        float wv = Wo[k * 64 + lane];
        acc1 += e1[base + k] * wv;
        acc2 += e2[base + k] * wv;
    }
    float u = uo[lane];
    float t1 = tanhf(acc1) * u;
    float t2 = tanhf(acc2) * u;
    #pragma unroll
    for (int off = 32; off; off >>= 1) {
        t1 += __shfl_xor(t1, off);
        t2 += __shfl_xor(t2, off);
    }
    float m = fmaxf(t1, t2);
    float a1 = expf(t1 - m), a2 = expf(t2 - m);
    float s = a1 + a2;
    a1 /= s; a2 /= s;

    emb[base + lane] = a1 * e1v + a2 * e2v;
    if (lane == 0) {
        alpha[(size_t)node * 2 + 0] = a1;
        alpha[(size_t)node * 2 + 1] = a2;
    }
}

extern "C" void kernel_launch(void* const* d_in, const int* in_sizes, int n_in,
                              void* d_out, int out_size, void* d_ws, size_t ws_size,
                              hipStream_t stream) {
    const float* omics1 = (const float*)d_in[0];
    const float* omics2 = (const float*)d_in[1];
    const int*   ei1    = (const int*)d_in[2];
    const float* ew1    = (const float*)d_in[3];
    const int*   ei2    = (const int*)d_in[4];
    const float* ew2    = (const float*)d_in[5];
    const float* Wenc1  = (const float*)d_in[6];
    const float* Wenc2  = (const float*)d_in[7];
    const float* womega = (const float*)d_in[8];
    const float* uomega = (const float*)d_in[9];
    const float* Wdec1  = (const float*)d_in[10];
    const float* Wdec2  = (const float*)d_in[11];

    float* out  = (float*)d_out;
    float* e1   = out;
    float* e2   = e1 + (size_t)NN * 64;
    float* emb  = e2 + (size_t)NN * 64;
    float* alph = emb + (size_t)NN * 64;
    float* d1   = alph + (size_t)NN * 2;
    float* d2   = d1 + (size_t)NN * 2000;

    // workspace layout
    char* w = (char*)d_ws;
    float* h1  = (float*)w;                w += (size_t)NN * 64 * 4;   // reused as s1
    float* h2  = (float*)w;                w += (size_t)NN * 64 * 4;   // reused as s2
    int*   cnt1 = (int*)w;                 w += (size_t)NN * 4;
    int*   cnt2 = (int*)w;                 w += (size_t)NN * 4;
    int*   rp1  = (int*)w;                 w += (size_t)(NN + 1) * 4;
    int*   rp2  = (int*)w;                 w += (size_t)(NN + 1) * 4;
    int*   cur1 = (int*)w;                 w += (size_t)NN * 4;
    int*   cur2 = (int*)w;                 w += (size_t)NN * 4;
    int*   sc1  = (int*)w;                 w += (size_t)NE * 4;
    float* sw1  = (float*)w;               w += (size_t)NE * 4;
    int*   sc2  = (int*)w;                 w += (size_t)NE * 4;
    float* sw2  = (float*)w;               w += (size_t)NE * 4;

    dim3 b256(256);

    // ---- CSR build (both edge sets) ----
    zero_i32<<<dim3((2 * NN + 255) / 256), b256, 0, stream>>>(cnt1, 2 * NN);  // cnt1,cnt2 contiguous
    hist2<<<dim3((2 * NE + 255) / 256), b256, 0, stream>>>(ei1, ei2, cnt1, cnt2);
    scan2<<<dim3(2), dim3(1024), 0, stream>>>(cnt1, cnt2, rp1, rp2, cur1, cur2, NN);
    scatter2<<<dim3((2 * NE + 255) / 256), b256, 0, stream>>>(
        ei1, ei1 + NE, ew1, cur1, sc1, sw1,
        ei2, ei2 + NE, ew2, cur2, sc2, sw2);

    // ---- encoders ----
    gemm_enc<<<dim3((NN + 63) / 64), b256, 0, stream>>>(omics1, Wenc1, h1, NN, 2000);
    gemm_enc<<<dim3((NN + 63) / 64), b256, 0, stream>>>(omics2, Wenc2, h2, NN, 500);
    spmm_csr<<<dim3((NN + 3) / 4), b256, 0, stream>>>(rp1, sc1, sw1, h1, e1, NN);
    spmm_csr<<<dim3((NN + 3) / 4), b256, 0, stream>>>(rp2, sc2, sw2, h2, e2, NN);

    // ---- attention fusion ----
    attn_fuse<<<dim3((NN + 3) / 4), b256, 0, stream>>>(e1, e2, womega, uomega, emb, alph, NN);

    // ---- decoder spmm (reuse h1/h2 as s1/s2) ----
    spmm_csr<<<dim3((NN + 3) / 4), b256, 0, stream>>>(rp1, sc1, sw1, emb, h1, NN);
    spmm_csr<<<dim3((NN + 3) / 4), b256, 0, stream>>>(rp2, sc2, sw2, emb, h2, NN);

    // ---- decoders ----
    gemm_dec<<<dim3((NN + 63) / 64, 16), b256, 0, stream>>>(h1, Wdec1, d1, NN, 2000);
    gemm_dec<<<dim3((NN + 63) / 64, 4), b256, 0, stream>>>(h2, Wdec2, d2, NN, 500);
}

// Round 3
// 903.979 us; speedup vs baseline: 1.5402x; 1.0468x over previous
//
#include <hip/hip_runtime.h>
#include <math.h>

#define NN 50000
#define NE 800000

typedef __attribute__((ext_vector_type(8))) short bf16x8;
typedef __attribute__((ext_vector_type(4))) float f32x4;

__device__ __forceinline__ ushort f2bf(float f) {
    union { float f; unsigned u; } v; v.f = f;
    unsigned r = v.u + 0x7FFFu + ((v.u >> 16) & 1u);   // RNE
    return (ushort)(r >> 16);
}

__device__ __forceinline__ bf16x8 cvt8(const float* __restrict__ p) {
    f32x4 a = *(const f32x4*)p;
    f32x4 b = *(const f32x4*)(p + 4);
    ushort u[8] = { f2bf(a.x), f2bf(a.y), f2bf(a.z), f2bf(a.w),
                    f2bf(b.x), f2bf(b.y), f2bf(b.z), f2bf(b.w) };
    return *(bf16x8*)u;
}

// ============ fragment precompute: src[K][Nc] f32 -> bf16 MFMA B-fragments ============
// dst element t = ((g*nct + ct)*64 + lane), 8 bf16 per thread:
//   value(j) = src[g*32 + (lane>>4)*8 + j][ct*16 + (lane&15)]   (0 beyond K/Nc)
__device__ __forceinline__ void frag_one(const float* __restrict__ src, ushort* __restrict__ dst,
                                         int K, int Nc, int t) {
    int nct = (Nc + 15) >> 4;
    int lane = t & 63, rest = t >> 6;
    int ct = rest % nct, g = rest / nct;
    int col = ct * 16 + (lane & 15);
    int kb = g * 32 + (lane >> 4) * 8;
    ushort u[8];
    #pragma unroll
    for (int j = 0; j < 8; ++j) {
        int k = kb + j;
        float v = (k < K && col < Nc) ? src[(size_t)k * Nc + col] : 0.f;
        u[j] = f2bf(v);
    }
    *(bf16x8*)&dst[(size_t)t * 8] = *(bf16x8*)u;
}

__global__ __launch_bounds__(256) void make_frag4(
    const float* __restrict__ s0, ushort* __restrict__ d0, int K0, int N0, int n0,
    const float* __restrict__ s1, ushort* __restrict__ d1, int K1, int N1, int n1,
    const float* __restrict__ s2, ushort* __restrict__ d2, int K2, int N2, int n2,
    const float* __restrict__ s3, ushort* __restrict__ d3, int K3, int N3, int n3) {
    int t = blockIdx.x * 256 + threadIdx.x;
    if (t < n0) { frag_one(s0, d0, K0, N0, t); return; } t -= n0;
    if (t < n1) { frag_one(s1, d1, K1, N1, t); return; } t -= n1;
    if (t < n2) { frag_one(s2, d2, K2, N2, t); return; } t -= n2;
    if (t < n3) { frag_one(s3, d3, K3, N3, t); }
}

// ============ CSR build ============
__global__ __launch_bounds__(256) void hist2(const int* __restrict__ r1, const int* __restrict__ r2,
                                             int* __restrict__ c1, int* __restrict__ c2) {
    int i = blockIdx.x * 256 + threadIdx.x;
    if (i < NE) atomicAdd(&c1[r1[i]], 1);
    else { i -= NE; if (i < NE) atomicAdd(&c2[r2[i]], 1); }
}

__global__ __launch_bounds__(1024) void scan2(const int* __restrict__ c1, const int* __restrict__ c2,
                                              int* __restrict__ rp1, int* __restrict__ rp2,
                                              int* __restrict__ cur1, int* __restrict__ cur2, int n) {
    const int* counts = blockIdx.x == 0 ? c1 : c2;
    int* rowptr = blockIdx.x == 0 ? rp1 : rp2;
    int* cursor = blockIdx.x == 0 ? cur1 : cur2;

    __shared__ int wsum[16];
    int t = threadIdx.x;
    const int chunk = (n + 1023) / 1024;
    int lo = t * chunk; int hi = lo + chunk; if (hi > n) hi = n; if (lo > n) lo = n;
    int s = 0;
    for (int i = lo; i < hi; ++i) s += counts[i];

    int lane = t & 63, w = t >> 6;
    int incl = s;
    #pragma unroll
    for (int off = 1; off < 64; off <<= 1) {
        int v = __shfl_up(incl, off);
        if (lane >= off) incl += v;
    }
    if (lane == 63) wsum[w] = incl;
    __syncthreads();
    if (w == 0 && lane < 16) {
        int v = wsum[lane];
        int iv = v;
        #pragma unroll
        for (int off = 1; off < 16; off <<= 1) {
            int u = __shfl_up(iv, off);
            if (lane >= off) iv += u;
        }
        wsum[lane] = iv - v;   // exclusive
    }
    __syncthreads();
    int off = wsum[w] + incl - s;
    for (int i = lo; i < hi; ++i) { rowptr[i] = off; cursor[i] = off; off += counts[i]; }
    if (t == 1023) rowptr[n] = off;
}

__global__ __launch_bounds__(256) void scatter2(
    const int* __restrict__ r1, const int* __restrict__ ce1, const float* __restrict__ w1,
    int* __restrict__ cur1, int* __restrict__ sc1, float* __restrict__ sw1,
    const int* __restrict__ r2, const int* __restrict__ ce2, const float* __restrict__ w2,
    int* __restrict__ cur2, int* __restrict__ sc2, float* __restrict__ sw2) {
    int i = blockIdx.x * 256 + threadIdx.x;
    if (i < NE) {
        int p = atomicAdd(&cur1[r1[i]], 1);
        sc1[p] = ce1[i]; sw1[p] = w1[i];
    } else {
        i -= NE;
        if (i < NE) {
            int p = atomicAdd(&cur2[r2[i]], 1);
            sc2[p] = ce2[i]; sw2[p] = w2[i];
        }
    }
}

// ============ CSR spmm, both edge sets in one launch ============
__global__ __launch_bounds__(256) void spmm2(
    const int* __restrict__ rp1, const int* __restrict__ sc1, const float* __restrict__ sw1,
    const float* __restrict__ x1, float* __restrict__ o1,
    const int* __restrict__ rp2, const int* __restrict__ sc2, const float* __restrict__ sw2,
    const float* __restrict__ x2, float* __restrict__ o2) {
    const int lane = threadIdx.x & 63;
    int gw = (blockIdx.x * 256 + threadIdx.x) >> 6;
    if (gw >= 2 * NN) return;
    const int* rp; const int* sc; const float* sw; const float* x; float* o; int row;
    if (gw < NN) { rp = rp1; sc = sc1; sw = sw1; x = x1; o = o1; row = gw; }
    else         { rp = rp2; sc = sc2; sw = sw2; x = x2; o = o2; row = gw - NN; }
    int beg = rp[row], end = rp[row + 1];
    float acc = 0.f;
    int i = beg;
    for (; i + 3 < end; i += 4) {          // 4 independent gathers in flight
        int c0 = sc[i], c1 = sc[i + 1], c2 = sc[i + 2], c3 = sc[i + 3];
        float w0 = sw[i], w1 = sw[i + 1], w2 = sw[i + 2], w3 = sw[i + 3];
        float g0 = x[(size_t)c0 * 64 + lane];
        float g1 = x[(size_t)c1 * 64 + lane];
        float g2 = x[(size_t)c2 * 64 + lane];
        float g3 = x[(size_t)c3 * 64 + lane];
        acc += w0 * g0; acc += w1 * g1; acc += w2 * g2; acc += w3 * g3;
    }
    for (; i < end; ++i) acc += sw[i] * x[(size_t)sc[i] * 64 + lane];
    o[(size_t)row * 64 + lane] = acc;
}

// ============ encoder GEMM: C[M,64] = A[M,K] @ B, no LDS, no barriers ============
// wave owns 16 rows; A-frags direct from global + inline cvt; B-frags from precomputed Bf.
__global__ __launch_bounds__(256) void gemm_enc3(
    const float* __restrict__ A1, const ushort* __restrict__ Bf1, float* __restrict__ C1, int K1,
    const float* __restrict__ A2, const ushort* __restrict__ Bf2, float* __restrict__ C2, int K2) {
    const int lane = threadIdx.x & 63;
    int gw = (blockIdx.x * 256 + threadIdx.x) >> 6;
    const int nw = (gridDim.x * 256) >> 6;
    const int tpset = NN / 16;                  // 3125 (exact)
    const int klo = (lane >> 4) * 8;

    for (int t = gw; t < 2 * tpset; t += nw) {
        const float* A; const ushort* Bf; float* C; int K, tile;
        if (t < tpset) { A = A1; Bf = Bf1; C = C1; K = K1; tile = t; }
        else           { A = A2; Bf = Bf2; C = C2; K = K2; tile = t - tpset; }
        const int arow = tile * 16 + (lane & 15);
        const float* aptr = A + (size_t)arow * K;
        const bf16x8* bv = (const bf16x8*)Bf;
        const int ng = (K + 31) >> 5;
        f32x4 acc[4] = {};
        #pragma unroll 2
        for (int g = 0; g < ng; ++g) {
            int kg = g * 32 + klo;
            float v[8];
            if (kg + 7 < K) {
                f32x4 a = *(const f32x4*)(aptr + kg);
                f32x4 b = *(const f32x4*)(aptr + kg + 4);
                v[0] = a.x; v[1] = a.y; v[2] = a.z; v[3] = a.w;
                v[4] = b.x; v[5] = b.y; v[6] = b.z; v[7] = b.w;
            } else {
                #pragma unroll
                for (int j = 0; j < 8; ++j) v[j] = (kg + j < K) ? aptr[kg + j] : 0.f;
            }
            ushort u[8];
            #pragma unroll
            for (int j = 0; j < 8; ++j) u[j] = f2bf(v[j]);
            bf16x8 af = *(bf16x8*)u;
            #pragma unroll
            for (int ct = 0; ct < 4; ++ct)
                acc[ct] = __builtin_amdgcn_mfma_f32_16x16x32_bf16(
                    af, bv[(g * 4 + ct) * 64 + lane], acc[ct], 0, 0, 0);
        }
        const int rbase = tile * 16 + (lane >> 4) * 4;
        const int cb = lane & 15;
        #pragma unroll
        for (int ct = 0; ct < 4; ++ct)
            #pragma unroll
            for (int r = 0; r < 4; ++r)
                C[(size_t)(rbase + r) * 64 + ct * 16 + cb] = acc[ct][r];
    }
}

// ============ decoder GEMM: C[M,Nc] = S[M,64] @ W, no LDS, no barriers ============
__global__ __launch_bounds__(256) void gemm_dec3(
    const float* __restrict__ S1, const ushort* __restrict__ Wf1, float* __restrict__ C1, int Nc1, int nct1,
    const float* __restrict__ S2, const ushort* __restrict__ Wf2, float* __restrict__ C2, int Nc2, int nct2) {
    const int lane = threadIdx.x & 63;
    int gw = (blockIdx.x * 256 + threadIdx.x) >> 6;
    const int nw = (gridDim.x * 256) >> 6;
    const int tpset = NN / 16;                  // 3125 (exact)
    const int klo = (lane >> 4) * 8;

    for (int t = gw; t < 2 * tpset; t += nw) {
        const float* S; const ushort* Wf; float* C; int Nc, nct, tile;
        if (t < tpset) { S = S1; Wf = Wf1; C = C1; Nc = Nc1; nct = nct1; tile = t; }
        else           { S = S2; Wf = Wf2; C = C2; Nc = Nc2; nct = nct2; tile = t - tpset; }
        const int arow = tile * 16 + (lane & 15);
        const float* sp = S + (size_t)arow * 64;
        bf16x8 af0 = cvt8(sp + klo);            // k in [klo, klo+8)
        bf16x8 af1 = cvt8(sp + 32 + klo);       // k in [32+klo, 32+klo+8)
        const bf16x8* wv = (const bf16x8*)Wf;
        const int rbase = tile * 16 + (lane >> 4) * 4;
        const int cb = lane & 15;
        #pragma unroll 2
        for (int ct = 0; ct < nct; ++ct) {
            f32x4 acc = {};
            acc = __builtin_amdgcn_mfma_f32_16x16x32_bf16(af0, wv[ct * 64 + lane], acc, 0, 0, 0);
            acc = __builtin_amdgcn_mfma_f32_16x16x32_bf16(af1, wv[(nct + ct) * 64 + lane], acc, 0, 0, 0);
            int col = ct * 16 + cb;
            if (col < Nc) {
                #pragma unroll
                for (int r = 0; r < 4; ++r)
                    C[(size_t)(rbase + r) * Nc + col] = acc[r];
            }
        }
    }
}

// ============ attention fusion ============
__global__ __launch_bounds__(256) void attn_fuse(
    const float* __restrict__ e1, const float* __restrict__ e2,
    const float* __restrict__ Wo, const float* __restrict__ uo,
    float* __restrict__ emb, float* __restrict__ alpha, int n) {
    const int lane = threadIdx.x & 63;
    const int node = (blockIdx.x * 256 + threadIdx.x) >> 6;
    if (node >= n) return;

    const size_t base = (size_t)node * 64;
    float e1v = e1[base + lane];
    float e2v = e2[base + lane];

    float acc1 = 0.f, acc2 = 0.f;
    for (int k = 0; k < 64; ++k) {
        float wv = Wo[k * 64 + lane];
        acc1 += e1[base + k] * wv;
        acc2 += e2[base + k] * wv;
    }
    float u = uo[lane];
    float t1 = tanhf(acc1) * u;
    float t2 = tanhf(acc2) * u;
    #pragma unroll
    for (int off = 32; off; off >>= 1) {
        t1 += __shfl_xor(t1, off);
        t2 += __shfl_xor(t2, off);
    }
    float m = fmaxf(t1, t2);
    float a1 = expf(t1 - m), a2 = expf(t2 - m);
    float s = a1 + a2;
    a1 /= s; a2 /= s;

    emb[base + lane] = a1 * e1v + a2 * e2v;
    if (lane == 0) {
        alpha[(size_t)node * 2 + 0] = a1;
        alpha[(size_t)node * 2 + 1] = a2;
    }
}

extern "C" void kernel_launch(void* const* d_in, const int* in_sizes, int n_in,
                              void* d_out, int out_size, void* d_ws, size_t ws_size,
                              hipStream_t stream) {
    const float* omics1 = (const float*)d_in[0];
    const float* omics2 = (const float*)d_in[1];
    const int*   ei1    = (const int*)d_in[2];
    const float* ew1    = (const float*)d_in[3];
    const int*   ei2    = (const int*)d_in[4];
    const float* ew2    = (const float*)d_in[5];
    const float* Wenc1  = (const float*)d_in[6];
    const float* Wenc2  = (const float*)d_in[7];
    const float* womega = (const float*)d_in[8];
    const float* uomega = (const float*)d_in[9];
    const float* Wdec1  = (const float*)d_in[10];
    const float* Wdec2  = (const float*)d_in[11];

    float* out  = (float*)d_out;
    float* e1   = out;
    float* e2   = e1 + (size_t)NN * 64;
    float* emb  = e2 + (size_t)NN * 64;
    float* alph = emb + (size_t)NN * 64;
    float* d1   = alph + (size_t)NN * 2;
    float* d2   = d1 + (size_t)NN * 2000;

    // fragment array thread counts
    const int nBf1 = 63 * 4 * 64;    // Wenc1: K=2000 -> ng 63, nct 4
    const int nBf2 = 16 * 4 * 64;    // Wenc2: K=500  -> ng 16
    const int nWf1 = 2 * 125 * 64;   // Wdec1: K=64 -> ng 2, Nc=2000 -> nct 125
    const int nWf2 = 2 * 32 * 64;    // Wdec2: Nc=500 -> nct 32

    // workspace layout
    char* w = (char*)d_ws;
    float* h1  = (float*)w;                w += (size_t)NN * 64 * 4;   // reused as s1
    float* h2  = (float*)w;                w += (size_t)NN * 64 * 4;   // reused as s2
    int*   cnt1 = (int*)w;                 w += (size_t)NN * 4;
    int*   cnt2 = (int*)w;                 w += (size_t)NN * 4;
    int*   rp1  = (int*)w;                 w += (size_t)(NN + 1) * 4;
    int*   rp2  = (int*)w;                 w += (size_t)(NN + 1) * 4 + 8;  // keep 16B align
    int*   cur1 = (int*)w;                 w += (size_t)NN * 4;
    int*   cur2 = (int*)w;                 w += (size_t)NN * 4;
    int*   sc1  = (int*)w;                 w += (size_t)NE * 4;
    float* sw1  = (float*)w;               w += (size_t)NE * 4;
    int*   sc2  = (int*)w;                 w += (size_t)NE * 4;
    float* sw2  = (float*)w;               w += (size_t)NE * 4;
    ushort* Bf1 = (ushort*)w;              w += (size_t)nBf1 * 8 * 2;
    ushort* Bf2 = (ushort*)w;              w += (size_t)nBf2 * 8 * 2;
    ushort* Wf1 = (ushort*)w;              w += (size_t)nWf1 * 8 * 2;
    ushort* Wf2 = (ushort*)w;              w += (size_t)nWf2 * 8 * 2;

    dim3 b256(256);

    // ---- B/W fragment precompute (one launch, all four) ----
    const int nfrag = nBf1 + nBf2 + nWf1 + nWf2;
    make_frag4<<<dim3((nfrag + 255) / 256), b256, 0, stream>>>(
        Wenc1, Bf1, 2000, 64, nBf1,
        Wenc2, Bf2, 500, 64, nBf2,
        Wdec1, Wf1, 64, 2000, nWf1,
        Wdec2, Wf2, 64, 500, nWf2);

    // ---- CSR build ----
    hipMemsetAsync(cnt1, 0, (size_t)2 * NN * 4, stream);   // cnt1,cnt2 contiguous
    hist2<<<dim3((2 * NE + 255) / 256), b256, 0, stream>>>(ei1, ei2, cnt1, cnt2);
    scan2<<<dim3(2), dim3(1024), 0, stream>>>(cnt1, cnt2, rp1, rp2, cur1, cur2, NN);
    scatter2<<<dim3((2 * NE + 255) / 256), b256, 0, stream>>>(
        ei1, ei1 + NE, ew1, cur1, sc1, sw1,
        ei2, ei2 + NE, ew2, cur2, sc2, sw2);

    // ---- encoders (both in one launch) ----
    gemm_enc3<<<dim3(2048), b256, 0, stream>>>(omics1, Bf1, h1, 2000, omics2, Bf2, h2, 500);
    spmm2<<<dim3(2 * NN / 4), b256, 0, stream>>>(rp1, sc1, sw1, h1, e1,
                                                 rp2, sc2, sw2, h2, e2);

    // ---- attention fusion ----
    attn_fuse<<<dim3((NN + 3) / 4), b256, 0, stream>>>(e1, e2, womega, uomega, emb, alph, NN);

    // ---- decoder spmm (reuse h1/h2 as s1/s2) ----
    spmm2<<<dim3(2 * NN / 4), b256, 0, stream>>>(rp1, sc1, sw1, emb, h1,
                                                 rp2, sc2, sw2, emb, h2);

    // ---- decoders (both in one launch) ----
    gemm_dec3<<<dim3(2048), b256, 0, stream>>>(h1, Wf1, d1, 2000, 125, h2, Wf2, d2, 500, 32);
}

// Round 5
// 865.727 us; speedup vs baseline: 1.6083x; 1.0442x over previous
//
#include <hip/hip_runtime.h>
#include <math.h>

#define NN 50000
#define NE 800000

typedef __attribute__((ext_vector_type(8))) short bf16x8;
typedef __attribute__((ext_vector_type(4))) float f32x4;

__device__ __forceinline__ ushort f2bf(float f) {
    union { float f; unsigned u; } v; v.f = f;
    unsigned r = v.u + 0x7FFFu + ((v.u >> 16) & 1u);   // RNE
    return (ushort)(r >> 16);
}

__device__ __forceinline__ float bf2f(ushort u) {
    union { unsigned u; float f; } v; v.u = ((unsigned)u) << 16;
    return v.f;
}

// ============ fragment precompute: src[K][Nc] f32 -> bf16 MFMA B-fragments ============
// dst element t = ((g*nct + ct)*64 + lane), 8 bf16 per thread:
//   value(j) = src[g*32 + (lane>>4)*8 + j][ct*16 + (lane&15)]   (0 beyond K/Nc)
__device__ __forceinline__ void frag_one(const float* __restrict__ src, ushort* __restrict__ dst,
                                         int K, int Nc, int t) {
    int nct = (Nc + 15) >> 4;
    int lane = t & 63, rest = t >> 6;
    int ct = rest % nct, g = rest / nct;
    int col = ct * 16 + (lane & 15);
    int kb = g * 32 + (lane >> 4) * 8;
    ushort u[8];
    #pragma unroll
    for (int j = 0; j < 8; ++j) {
        int k = kb + j;
        float v = (k < K && col < Nc) ? src[(size_t)k * Nc + col] : 0.f;
        u[j] = f2bf(v);
    }
    *(bf16x8*)&dst[(size_t)t * 8] = *(bf16x8*)u;
}

__global__ __launch_bounds__(256) void make_frag4(
    const float* __restrict__ s0, ushort* __restrict__ d0, int K0, int N0, int n0,
    const float* __restrict__ s1, ushort* __restrict__ d1, int K1, int N1, int n1,
    const float* __restrict__ s2, ushort* __restrict__ d2, int K2, int N2, int n2,
    const float* __restrict__ s3, ushort* __restrict__ d3, int K3, int N3, int n3) {
    int t = blockIdx.x * 256 + threadIdx.x;
    if (t < n0) { frag_one(s0, d0, K0, N0, t); return; } t -= n0;
    if (t < n1) { frag_one(s1, d1, K1, N1, t); return; } t -= n1;
    if (t < n2) { frag_one(s2, d2, K2, N2, t); return; } t -= n2;
    if (t < n3) { frag_one(s3, d3, K3, N3, t); }
}

// ============ CSR build ============
__global__ __launch_bounds__(256) void hist2(const int* __restrict__ r1, const int* __restrict__ r2,
                                             int* __restrict__ c1, int* __restrict__ c2) {
    int i = blockIdx.x * 256 + threadIdx.x;
    if (i < NE) atomicAdd(&c1[r1[i]], 1);
    else { i -= NE; if (i < NE) atomicAdd(&c2[r2[i]], 1); }
}

__global__ __launch_bounds__(1024) void scan2(const int* __restrict__ c1, const int* __restrict__ c2,
                                              int* __restrict__ rp1, int* __restrict__ rp2,
                                              int* __restrict__ cur1, int* __restrict__ cur2, int n) {
    const int* counts = blockIdx.x == 0 ? c1 : c2;
    int* rowptr = blockIdx.x == 0 ? rp1 : rp2;
    int* cursor = blockIdx.x == 0 ? cur1 : cur2;

    __shared__ int wsum[16];
    int t = threadIdx.x;
    const int chunk = (n + 1023) / 1024;
    int lo = t * chunk; int hi = lo + chunk; if (hi > n) hi = n; if (lo > n) lo = n;
    int s = 0;
    for (int i = lo; i < hi; ++i) s += counts[i];

    int lane = t & 63, w = t >> 6;
    int incl = s;
    #pragma unroll
    for (int off = 1; off < 64; off <<= 1) {
        int v = __shfl_up(incl, off);
        if (lane >= off) incl += v;
    }
    if (lane == 63) wsum[w] = incl;
    __syncthreads();
    if (w == 0 && lane < 16) {
        int v = wsum[lane];
        int iv = v;
        #pragma unroll
        for (int off = 1; off < 16; off <<= 1) {
            int u = __shfl_up(iv, off);
            if (lane >= off) iv += u;
        }
        wsum[lane] = iv - v;   // exclusive
    }
    __syncthreads();
    int off = wsum[w] + incl - s;
    for (int i = lo; i < hi; ++i) { rowptr[i] = off; cursor[i] = off; off += counts[i]; }
    if (t == 1023) rowptr[n] = off;
}

// packed payload: {col, weight_bits}
__global__ __launch_bounds__(256) void scatter2(
    const int* __restrict__ r1, const int* __restrict__ ce1, const float* __restrict__ w1,
    int* __restrict__ cur1, int2* __restrict__ scw1,
    const int* __restrict__ r2, const int* __restrict__ ce2, const float* __restrict__ w2,
    int* __restrict__ cur2, int2* __restrict__ scw2) {
    int i = blockIdx.x * 256 + threadIdx.x;
    if (i < NE) {
        int p = atomicAdd(&cur1[r1[i]], 1);
        scw1[p] = make_int2(ce1[i], __float_as_int(w1[i]));
    } else {
        i -= NE;
        if (i < NE) {
            int p = atomicAdd(&cur2[r2[i]], 1);
            scw2[p] = make_int2(ce2[i], __float_as_int(w2[i]));
        }
    }
}

// ============ encoder GEMM: h_bf16[M,64] = A[M,K] @ B (frag), no LDS ============
__global__ __launch_bounds__(256) void gemm_enc3(
    const float* __restrict__ A1, const ushort* __restrict__ Bf1, ushort* __restrict__ C1, int K1,
    const float* __restrict__ A2, const ushort* __restrict__ Bf2, ushort* __restrict__ C2, int K2) {
    const int lane = threadIdx.x & 63;
    int gw = (blockIdx.x * 256 + threadIdx.x) >> 6;
    const int nw = (gridDim.x * 256) >> 6;
    const int tpset = NN / 16;                  // 3125 (exact)
    const int klo = (lane >> 4) * 8;

    for (int t = gw; t < 2 * tpset; t += nw) {
        const float* A; const ushort* Bf; ushort* C; int K, tile;
        if (t < tpset) { A = A1; Bf = Bf1; C = C1; K = K1; tile = t; }
        else           { A = A2; Bf = Bf2; C = C2; K = K2; tile = t - tpset; }
        const int arow = tile * 16 + (lane & 15);
        const float* aptr = A + (size_t)arow * K;
        const bf16x8* bv = (const bf16x8*)Bf;
        const int ng = (K + 31) >> 5;
        f32x4 acc[4] = {};
        #pragma unroll 2
        for (int g = 0; g < ng; ++g) {
            int kg = g * 32 + klo;
            float v[8];
            if (kg + 7 < K) {
                f32x4 a = *(const f32x4*)(aptr + kg);
                f32x4 b = *(const f32x4*)(aptr + kg + 4);
                v[0] = a.x; v[1] = a.y; v[2] = a.z; v[3] = a.w;
                v[4] = b.x; v[5] = b.y; v[6] = b.z; v[7] = b.w;
            } else {
                #pragma unroll
                for (int j = 0; j < 8; ++j) v[j] = (kg + j < K) ? aptr[kg + j] : 0.f;
            }
            ushort u[8];
            #pragma unroll
            for (int j = 0; j < 8; ++j) u[j] = f2bf(v[j]);
            bf16x8 af = *(bf16x8*)u;
            #pragma unroll
            for (int ct = 0; ct < 4; ++ct)
                acc[ct] = __builtin_amdgcn_mfma_f32_16x16x32_bf16(
                    af, bv[(g * 4 + ct) * 64 + lane], acc[ct], 0, 0, 0);
        }
        const int rbase = tile * 16 + (lane >> 4) * 4;
        const int cb = lane & 15;
        #pragma unroll
        for (int ct = 0; ct < 4; ++ct)
            #pragma unroll
            for (int r = 0; r < 4; ++r)
                C[(size_t)(rbase + r) * 64 + ct * 16 + cb] = f2bf(acc[ct][r]);
    }
}

// ============ fused encoder-spmm + attention, wave per node ============
__global__ __launch_bounds__(256) void spmm_attn(
    const int* __restrict__ rp1, const int2* __restrict__ scw1, const ushort* __restrict__ x1,
    const int* __restrict__ rp2, const int2* __restrict__ scw2, const ushort* __restrict__ x2,
    const float* __restrict__ Wo, const float* __restrict__ uo,
    float* __restrict__ e1, float* __restrict__ e2,
    float* __restrict__ emb, ushort* __restrict__ embb, float* __restrict__ alpha) {
    const int lane = threadIdx.x & 63;
    const int node = (blockIdx.x * 256 + threadIdx.x) >> 6;
    if (node >= NN) return;

    float ev[2];
    #pragma unroll
    for (int s = 0; s < 2; ++s) {
        const int* rp = s ? rp2 : rp1;
        const int2* scw = s ? scw2 : scw1;
        const ushort* x = s ? x2 : x1;
        int beg = rp[node], end = rp[node + 1];
        float acc = 0.f;
        int i = beg;
        for (; i + 3 < end; i += 4) {
            int2 p0 = scw[i], p1 = scw[i + 1], p2 = scw[i + 2], p3 = scw[i + 3];
            float g0 = bf2f(x[(size_t)p0.x * 64 + lane]);
            float g1 = bf2f(x[(size_t)p1.x * 64 + lane]);
            float g2 = bf2f(x[(size_t)p2.x * 64 + lane]);
            float g3 = bf2f(x[(size_t)p3.x * 64 + lane]);
            acc += __int_as_float(p0.y) * g0;
            acc += __int_as_float(p1.y) * g1;
            acc += __int_as_float(p2.y) * g2;
            acc += __int_as_float(p3.y) * g3;
        }
        for (; i < end; ++i) {
            int2 p = scw[i];
            acc += __int_as_float(p.y) * bf2f(x[(size_t)p.x * 64 + lane]);
        }
        ev[s] = acc;
    }

    // attention: acc_s[lane] = sum_k e_s[k] * Wo[k][lane]  (e_s[k] lives in lane k)
    float acc1 = 0.f, acc2 = 0.f;
    #pragma unroll 8
    for (int k = 0; k < 64; ++k) {
        float wv = Wo[k * 64 + lane];
        acc1 = fmaf(__shfl(ev[0], k), wv, acc1);
        acc2 = fmaf(__shfl(ev[1], k), wv, acc2);
    }
    float u = uo[lane];
    float t1 = tanhf(acc1) * u;
    float t2 = tanhf(acc2) * u;
    #pragma unroll
    for (int off = 32; off; off >>= 1) {
        t1 += __shfl_xor(t1, off);
        t2 += __shfl_xor(t2, off);
    }
    float m = fmaxf(t1, t2);
    float a1 = expf(t1 - m), a2 = expf(t2 - m);
    float sden = a1 + a2;
    a1 /= sden; a2 /= sden;

    const size_t base = (size_t)node * 64;
    float ec = a1 * ev[0] + a2 * ev[1];
    e1[base + lane] = ev[0];
    e2[base + lane] = ev[1];
    emb[base + lane] = ec;
    embb[base + lane] = f2bf(ec);
    if (lane == 0) *(float2*)&alpha[(size_t)node * 2] = make_float2(a1, a2);
}

// ============ decoder spmm (both sets, shared x), bf16 out ============
__global__ __launch_bounds__(256) void spmm_dec(
    const int* __restrict__ rp1, const int2* __restrict__ scw1,
    const int* __restrict__ rp2, const int2* __restrict__ scw2,
    const ushort* __restrict__ xb, ushort* __restrict__ s1b, ushort* __restrict__ s2b) {
    const int lane = threadIdx.x & 63;
    int gw = (blockIdx.x * 256 + threadIdx.x) >> 6;
    if (gw >= 2 * NN) return;
    const int* rp; const int2* scw; ushort* o; int row;
    if (gw < NN) { rp = rp1; scw = scw1; o = s1b; row = gw; }
    else         { rp = rp2; scw = scw2; o = s2b; row = gw - NN; }
    int beg = rp[row], end = rp[row + 1];
    float acc = 0.f;
    int i = beg;
    for (; i + 3 < end; i += 4) {
        int2 p0 = scw[i], p1 = scw[i + 1], p2 = scw[i + 2], p3 = scw[i + 3];
        float g0 = bf2f(xb[(size_t)p0.x * 64 + lane]);
        float g1 = bf2f(xb[(size_t)p1.x * 64 + lane]);
        float g2 = bf2f(xb[(size_t)p2.x * 64 + lane]);
        float g3 = bf2f(xb[(size_t)p3.x * 64 + lane]);
        acc += __int_as_float(p0.y) * g0;
        acc += __int_as_float(p1.y) * g1;
        acc += __int_as_float(p2.y) * g2;
        acc += __int_as_float(p3.y) * g3;
    }
    for (; i < end; ++i) {
        int2 p = scw[i];
        acc += __int_as_float(p.y) * bf2f(xb[(size_t)p.x * 64 + lane]);
    }
    o[(size_t)row * 64 + lane] = f2bf(acc);
}

// ============ decoder GEMM: C[M,Nc] = S_bf16[M,64] @ W (frag), no LDS ============
__global__ __launch_bounds__(256) void gemm_dec3(
    const ushort* __restrict__ S1, const ushort* __restrict__ Wf1, float* __restrict__ C1, int Nc1, int nct1,
    const ushort* __restrict__ S2, const ushort* __restrict__ Wf2, float* __restrict__ C2, int Nc2, int nct2) {
    const int lane = threadIdx.x & 63;
    int gw = (blockIdx.x * 256 + threadIdx.x) >> 6;
    const int nw = (gridDim.x * 256) >> 6;
    const int tpset = NN / 16;                  // 3125 (exact)
    const int klo = (lane >> 4) * 8;

    for (int t = gw; t < 2 * tpset; t += nw) {
        const ushort* S; const ushort* Wf; float* C; int Nc, nct, tile;
        if (t < tpset) { S = S1; Wf = Wf1; C = C1; Nc = Nc1; nct = nct1; tile = t; }
        else           { S = S2; Wf = Wf2; C = C2; Nc = Nc2; nct = nct2; tile = t - tpset; }
        const int arow = tile * 16 + (lane & 15);
        const ushort* sp = S + (size_t)arow * 64;
        bf16x8 af0 = *(const bf16x8*)(sp + klo);        // k in [klo, klo+8)
        bf16x8 af1 = *(const bf16x8*)(sp + 32 + klo);   // k in [32+klo, ...)
        const bf16x8* wv = (const bf16x8*)Wf;
        const int rbase = tile * 16 + (lane >> 4) * 4;
        const int cb = lane & 15;
        #pragma unroll 2
        for (int ct = 0; ct < nct; ++ct) {
            f32x4 acc = {};
            acc = __builtin_amdgcn_mfma_f32_16x16x32_bf16(af0, wv[ct * 64 + lane], acc, 0, 0, 0);
            acc = __builtin_amdgcn_mfma_f32_16x16x32_bf16(af1, wv[(nct + ct) * 64 + lane], acc, 0, 0, 0);
            int col = ct * 16 + cb;
            if (col < Nc) {                       // partial last tile (Nc=500: cols 500..511 masked)
                #pragma unroll
                for (int r = 0; r < 4; ++r)
                    C[(size_t)(rbase + r) * Nc + col] = acc[r];
            }
        }
    }
}

extern "C" void kernel_launch(void* const* d_in, const int* in_sizes, int n_in,
                              void* d_out, int out_size, void* d_ws, size_t ws_size,
                              hipStream_t stream) {
    const float* omics1 = (const float*)d_in[0];
    const float* omics2 = (const float*)d_in[1];
    const int*   ei1    = (const int*)d_in[2];
    const float* ew1    = (const float*)d_in[3];
    const int*   ei2    = (const int*)d_in[4];
    const float* ew2    = (const float*)d_in[5];
    const float* Wenc1  = (const float*)d_in[6];
    const float* Wenc2  = (const float*)d_in[7];
    const float* womega = (const float*)d_in[8];
    const float* uomega = (const float*)d_in[9];
    const float* Wdec1  = (const float*)d_in[10];
    const float* Wdec2  = (const float*)d_in[11];

    float* out  = (float*)d_out;
    float* e1   = out;
    float* e2   = e1 + (size_t)NN * 64;
    float* emb  = e2 + (size_t)NN * 64;
    float* alph = emb + (size_t)NN * 64;
    float* d1   = alph + (size_t)NN * 2;
    float* d2   = d1 + (size_t)NN * 2000;

    // fragment array thread counts
    const int nBf1 = 63 * 4 * 64;    // Wenc1: K=2000 -> ng 63, nct 4
    const int nBf2 = 16 * 4 * 64;    // Wenc2: K=500  -> ng 16
    const int nWf1 = 2 * 125 * 64;   // Wdec1: K=64 -> ng 2, Nc=2000 -> nct 125
    const int nWf2 = 2 * 32 * 64;    // Wdec2: Nc=500 -> nct 32

    // workspace layout (all offsets 16B-aligned)
    char* w = (char*)d_ws;
    ushort* h1b = (ushort*)w;              w += (size_t)NN * 64 * 2;   // enc1 out (bf16)
    ushort* h2b = (ushort*)w;              w += (size_t)NN * 64 * 2;
    ushort* embb = (ushort*)w;             w += (size_t)NN * 64 * 2;
    ushort* s1b = (ushort*)w;              w += (size_t)NN * 64 * 2;
    ushort* s2b = (ushort*)w;              w += (size_t)NN * 64 * 2;
    int*   cnt1 = (int*)w;                 w += (size_t)NN * 4;
    int*   cnt2 = (int*)w;                 w += (size_t)NN * 4;
    int*   rp1  = (int*)w;                 w += (size_t)(NN + 1) * 4 + 12;
    int*   rp2  = (int*)w;                 w += (size_t)(NN + 1) * 4 + 12;
    int*   cur1 = (int*)w;                 w += (size_t)NN * 4;
    int*   cur2 = (int*)w;                 w += (size_t)NN * 4;
    int2*  scw1 = (int2*)w;                w += (size_t)NE * 8;
    int2*  scw2 = (int2*)w;                w += (size_t)NE * 8;
    ushort* Bf1 = (ushort*)w;              w += (size_t)nBf1 * 8 * 2;
    ushort* Bf2 = (ushort*)w;              w += (size_t)nBf2 * 8 * 2;
    ushort* Wf1 = (ushort*)w;              w += (size_t)nWf1 * 8 * 2;
    ushort* Wf2 = (ushort*)w;              w += (size_t)nWf2 * 8 * 2;

    dim3 b256(256);

    // ---- B/W fragment precompute ----
    const int nfrag = nBf1 + nBf2 + nWf1 + nWf2;
    make_frag4<<<dim3((nfrag + 255) / 256), b256, 0, stream>>>(
        Wenc1, Bf1, 2000, 64, nBf1,
        Wenc2, Bf2, 500, 64, nBf2,
        Wdec1, Wf1, 64, 2000, nWf1,
        Wdec2, Wf2, 64, 500, nWf2);

    // ---- CSR build ----
    hipMemsetAsync(cnt1, 0, (size_t)2 * NN * 4, stream);   // cnt1,cnt2 contiguous
    hist2<<<dim3((2 * NE + 255) / 256), b256, 0, stream>>>(ei1, ei2, cnt1, cnt2);
    scan2<<<dim3(2), dim3(1024), 0, stream>>>(cnt1, cnt2, rp1, rp2, cur1, cur2, NN);
    scatter2<<<dim3((2 * NE + 255) / 256), b256, 0, stream>>>(
        ei1, ei1 + NE, ew1, cur1, scw1,
        ei2, ei2 + NE, ew2, cur2, scw2);

    // ---- encoders (both in one launch, bf16 out) ----
    gemm_enc3<<<dim3(2048), b256, 0, stream>>>(omics1, Bf1, h1b, 2000, omics2, Bf2, h2b, 500);

    // ---- fused encoder-spmm + attention ----
    spmm_attn<<<dim3((NN + 3) / 4), b256, 0, stream>>>(
        rp1, scw1, h1b, rp2, scw2, h2b, womega, uomega, e1, e2, emb, embb, alph);

    // ---- decoder spmm (shared x = embb) ----
    spmm_dec<<<dim3(2 * NN / 4), b256, 0, stream>>>(rp1, scw1, rp2, scw2, embb, s1b, s2b);

    // ---- decoders (both in one launch) ----
    gemm_dec3<<<dim3(2048), b256, 0, stream>>>(s1b, Wf1, d1, 2000, 125, s2b, Wf2, d2, 500, 32);
}